// Round 2
// baseline (343.703 us; speedup 1.0000x reference)
//
#include <hip/hip_runtime.h>
#include <hip/hip_bf16.h>
#include <cstdint>

// ---------------------------------------------------------------------------
// TempoSpikeSelfAttention on MI355X (gfx950), bf16-MFMA pipeline.  v5
//   dims: T=4 B=4 N=1024 D=768 H=12 Dh=64 -> M = T*B*N = 16384 rows
// Pipeline (v5: transpose_v fused into QKV GEMM epilogue; single cast kernel):
//   1. cast_all: x, Wq|Wk|Wv (concat), Wo -> bf16 (one dispatch)
//   2. QKV GEMM (m97 structure): QKV[16384, 2304] bf16, bias fused.
//      Q/K column-blocks -> QKV row-major; V column-blocks -> written
//      TRANSPOSED straight to Vt[(tb*12+h)*64+d][n] (8B uint2 per thread;
//      per-wave footprint is a dense 64x128B region so L2 coalesces).
//   3. attn32 v4: grid (192 heads, 4 qt); 256 q/block; reg-pipelined K/V
//      staging; S^T = K Q^T (mfma 32x32x16); P C-layout -> B-layout in regs
//      via v_permlane32_swap_b32; octx += V^T P; L1-normalize in regs.
//   4. O GEMM: out = CTX @ Wo^T + bo -> fp32 d_out
// ---------------------------------------------------------------------------

typedef __attribute__((ext_vector_type(8))) short short8;     // 8 bf16 = 4 VGPR
typedef __attribute__((ext_vector_type(4))) float float4v;    // 16x16 acc
typedef __attribute__((ext_vector_type(16))) float float16v;  // 32x32 acc

__device__ __forceinline__ unsigned short f2bf(float f) {
  unsigned int u = __float_as_uint(f);
  u = (u + 0x7fffu + ((u >> 16) & 1u)) >> 16;   // RNE
  return (unsigned short)u;
}

// pack two f32 -> two bf16 (round-half-away) in one v_perm_b32
__device__ __forceinline__ unsigned int pkbf(float a, float b) {
  unsigned int ua = __float_as_uint(a) + 0x8000u;
  unsigned int ub = __float_as_uint(b) + 0x8000u;
  return __builtin_amdgcn_perm(ub, ua, 0x07060302u);  // [bf(a) lo16 | bf(b) hi16]
}

// async global->LDS, 16B per lane; LDS dest = wave-uniform base + lane*16
__device__ __forceinline__ void gld_lds16(const void* g, void* lds) {
  __builtin_amdgcn_global_load_lds(
      (__attribute__((address_space(1))) void*)(uintptr_t)g,
      (__attribute__((address_space(3))) void*)(uint32_t)(uintptr_t)lds,
      16, 0, 0);
}

// ---------------------------------------------------------------------------
// One dispatch for all fp32->bf16 casts. Block-uniform routing:
//   blocks [0,12288)        : x   (3145728 float4)
//   blocks [12288,12288+576): Wq -> WQKV[0]
//   next 576                : Wk -> WQKV+589824
//   next 576                : Wv -> WQKV+1179648
//   next 576                : Wo -> WOb
// All segments are exact multiples of 256 threads * float4 -> no tails.
__global__ __launch_bounds__(256) void cast_all(
    const float* __restrict__ x,  const float* __restrict__ Wq,
    const float* __restrict__ Wk, const float* __restrict__ Wv,
    const float* __restrict__ Wo, unsigned short* __restrict__ XBF,
    unsigned short* __restrict__ WQKV, unsigned short* __restrict__ WOb) {
  const int bid = blockIdx.x;
  const float* src;
  unsigned short* dst;
  int i;
  if (bid < 12288) {
    src = x; dst = XBF; i = bid * 256 + threadIdx.x;
  } else {
    const int wb = bid - 12288;          // 0..2303
    const int which = wb / 576;
    i = (wb % 576) * 256 + threadIdx.x;  // < 147456
    src = (which == 0) ? Wq : (which == 1) ? Wk : (which == 2) ? Wv : Wo;
    dst = (which == 0) ? WQKV
        : (which == 1) ? WQKV + 589824
        : (which == 2) ? WQKV + 1179648 : WOb;
  }
  float4 f = reinterpret_cast<const float4*>(src)[i];
  ushort4 o;
  o.x = f2bf(f.x); o.y = f2bf(f.y); o.z = f2bf(f.z); o.w = f2bf(f.w);
  reinterpret_cast<ushort4*>(dst)[i] = o;
}

// ---------------------------------------------------------------------------
// C[i,j] = sum_k A[i,k] * Bt[j,k] + bias[j].  K=768 fixed. 128x128 tile, BK=32.
// 4 waves in 2x2, each 64x64 (4x4 mfma 16x16x32 tiles).
// OUT_BF16 path: column-blocks with sel==2 (V) are written TRANSPOSED to Vt
// instead of Cb (attn only reads Q/K from QKV; V is consumed via Vt).
template <bool OUT_BF16>
__global__ __launch_bounds__(256) void gemm_bt(
    const unsigned short* __restrict__ A,   // [M,768] bf16
    const unsigned short* __restrict__ Bt,  // [N,768] bf16
    unsigned short* __restrict__ Cb,        // bf16 out [M,N]
    float* __restrict__ Cf,                 // f32 out  [M,N]
    unsigned short* __restrict__ Vt,        // bf16 out [(tb*12+h)*64+d][1024]
    const float* __restrict__ b0, const float* __restrict__ b1,
    const float* __restrict__ b2, int N) {
  constexpr int K = 768;
  __shared__ unsigned short As[128 * 32];   // packed: row stride 32 el (64 B)
  __shared__ unsigned short Bs[128 * 32];

  const int tid = threadIdx.x;
  const int lane = tid & 63;
  const int w = tid >> 6;
  const int wrow = w >> 1, wcol = w & 1;
  const int l15 = lane & 15, quad = lane >> 4;
  const int i0 = blockIdx.y * 128, j0 = blockIdx.x * 128;

  const unsigned short* ga = A + (size_t)(i0 + 32 * w + (lane >> 2)) * K + (lane & 3) * 8;
  const unsigned short* gb = Bt + (size_t)(j0 + 32 * w + (lane >> 2)) * K + (lane & 3) * 8;

  float4v acc[4][4];
#pragma unroll
  for (int a = 0; a < 4; ++a)
#pragma unroll
    for (int b = 0; b < 4; ++b) acc[a][b] = float4v{0.f, 0.f, 0.f, 0.f};

#pragma unroll 1
  for (int kt = 0; kt < K / 32; ++kt) {
    const unsigned short* pa = ga + kt * 32;
    const unsigned short* pb = gb + kt * 32;
    gld_lds16(pa, &As[(32 * w) * 32]);
    gld_lds16(pa + 16 * K, &As[(32 * w + 16) * 32]);
    gld_lds16(pb, &Bs[(32 * w) * 32]);
    gld_lds16(pb + 16 * K, &Bs[(32 * w + 16) * 32]);
    __syncthreads();   // drains vmcnt before barrier -> LDS tiles ready

    short8 af[4], bfr[4];
#pragma unroll
    for (int a = 0; a < 4; ++a)
      af[a] = *(const short8*)&As[(wrow * 64 + a * 16 + l15) * 32 + quad * 8];
#pragma unroll
    for (int b = 0; b < 4; ++b)
      bfr[b] = *(const short8*)&Bs[(wcol * 64 + b * 16 + l15) * 32 + quad * 8];
#pragma unroll
    for (int a = 0; a < 4; ++a)
#pragma unroll
      for (int b = 0; b < 4; ++b)
        acc[a][b] = __builtin_amdgcn_mfma_f32_16x16x32_bf16(af[a], bfr[b], acc[a][b], 0, 0, 0);
    __syncthreads();   // all reads done before next stage overwrites
  }

  const int sel = j0 / 768;
  const float* bp = (sel == 0) ? b0 : ((sel == 1) ? b1 : b2);
#pragma unroll
  for (int a = 0; a < 4; ++a) {
    const int row0 = i0 + wrow * 64 + a * 16 + quad * 4;
#pragma unroll
    for (int b = 0; b < 4; ++b) {
      const int col = j0 + wcol * 64 + b * 16 + l15;
      const float bias = bp[col - sel * 768];
      if (OUT_BF16 && sel == 2) {
        // V block -> transposed store into Vt.
        // rows row0..row0+3 share tb (row0 % 4 == 0, 1024 % 4 == 0).
        const int tb = row0 >> 10;
        const int n0 = row0 & 1023;            // multiple of 4 -> 8B aligned
        const int hd = col - 1536;             // h*64 + d
        const float v0 = acc[a][b][0] + bias;
        const float v1 = acc[a][b][1] + bias;
        const float v2 = acc[a][b][2] + bias;
        const float v3 = acc[a][b][3] + bias;
        uint2 u;
        u.x = (unsigned int)f2bf(v0) | ((unsigned int)f2bf(v1) << 16);
        u.y = (unsigned int)f2bf(v2) | ((unsigned int)f2bf(v3) << 16);
        *(uint2*)&Vt[((size_t)(tb * 768 + hd)) * 1024 + n0] = u;
      } else {
#pragma unroll
        for (int r = 0; r < 4; ++r) {
          const float v = acc[a][b][r] + bias;
          if (OUT_BF16)
            Cb[(size_t)(row0 + r) * N + col] = f2bf(v);
          else
            Cf[(size_t)(row0 + r) * N + col] = v;
        }
      }
    }
  }
}

// ---------------------------------------------------------------------------
// Attention v4. Grid (tbh=192, qt=4); 256 thr = 4 waves; wave = 64 q (2 x 32).
// Per kv-tile (64 keys):
//   barrier#1 (drains loads of kv) -> ds_write staged regs -> barrier#2 ->
//   issue loads kv+1 (hidden under compute) -> compute:
//     S^T = K.Q^T  (A=K rows from LDS, B=Q regs; C: row=kv, col=q=l31)
//     relu -> den (reg, q=l31); pack bf16; permlane32_swap -> PV B-frags
//     octx += V^T.P (A=Vt rows from LDS, B=P frags; C: row=d, col=q=l31)
// No P LDS traffic, no normalization scratch.
__global__ __launch_bounds__(256) void attn32(
    const unsigned short* __restrict__ qkv,  // [16384, 2304] bf16
    const unsigned short* __restrict__ vt,   // [(tbh)*64 + d][1024] bf16
    unsigned short* __restrict__ ctx) {      // [16384, 768] bf16
  __shared__ unsigned short Ks[64 * 72];     // [kv_local][d], padded
  __shared__ unsigned short Vs[64 * 72];     // [d][kv_local], padded

  const int tbh = blockIdx.x;                // same-head blocks: ids 192 apart
  const int qt = blockIdx.y;                 // -> same XCD (192 % 8 == 0)
  const int tb = tbh / 12, h = tbh % 12;
  const int tid = threadIdx.x, lane = tid & 63, w = tid >> 6;
  const int l31 = lane & 31, hl = lane >> 5;

  // ---- Q fragments: one-time scattered global loads ----
  short8 qf[2][4];   // [qs][kc]: B-op: lane holds Q[q=.. +l31][kc*16+hl*8+j]
#pragma unroll
  for (int qs = 0; qs < 2; ++qs) {
    const unsigned short* qp =
        qkv + (size_t)(tb * 1024 + qt * 256 + w * 64 + qs * 32 + l31) * 2304 +
        h * 64 + hl * 8;
#pragma unroll
    for (int kc = 0; kc < 4; ++kc) qf[qs][kc] = *(const short8*)(qp + kc * 16);
  }

  // ---- staging: 256 thr cover 64 rows x 8 chunks of 16B, 2 rows/thread ----
  const int srow = tid >> 3;   // 0..31 (and +32)
  const int sblk = tid & 7;
  const unsigned short* kcol =
      qkv + (size_t)(tb * 1024) * 2304 + 768 + h * 64 + sblk * 8;
  const unsigned short* vcol = vt + ((size_t)tbh * 64 + srow) * 1024 + sblk * 8;
  uint4 kr0, kr1, vr0, vr1;
  auto loadKV = [&](int kv) {
    const unsigned short* kp = kcol + (size_t)(kv * 64 + srow) * 2304;
    kr0 = *(const uint4*)kp;
    kr1 = *(const uint4*)(kp + 32 * 2304);
    const unsigned short* vp = vcol + kv * 64;
    vr0 = *(const uint4*)vp;
    vr1 = *(const uint4*)(vp + 32 * 1024);
  };

  float16v octx[2][2];   // [qs][dt]; C: row=d_local, col=q=l31
#pragma unroll
  for (int qs = 0; qs < 2; ++qs)
#pragma unroll
    for (int dt = 0; dt < 2; ++dt)
#pragma unroll
      for (int i = 0; i < 16; ++i) octx[qs][dt][i] = 0.f;
  float den[2] = {0.f, 0.f};

  loadKV(0);

#pragma unroll 1
  for (int kv = 0; kv < 16; ++kv) {
    __syncthreads();   // #1: all reads of tile kv-1 done; drains loads of kv
    *(uint4*)&Ks[srow * 72 + sblk * 8] = kr0;
    *(uint4*)&Ks[(srow + 32) * 72 + sblk * 8] = kr1;
    *(uint4*)&Vs[srow * 72 + sblk * 8] = vr0;
    *(uint4*)&Vs[(srow + 32) * 72 + sblk * 8] = vr1;
    __syncthreads();   // #2: writes visible (vmcnt trivially 0 here)
    if (kv < 15) loadKV(kv + 1);   // in flight across compute below

#pragma unroll
    for (int qs = 0; qs < 2; ++qs) {
      // S^T = K.Q^T, then relu+den+pack (C: col=q=l31, row=kv=4hl+(r)+8g+32mt)
      unsigned int pk[2][8];   // [mt][g*2+p]
#pragma unroll
      for (int mt = 0; mt < 2; ++mt) {
        float16v st;
#pragma unroll
        for (int i = 0; i < 16; ++i) st[i] = 0.f;
#pragma unroll
        for (int kc = 0; kc < 4; ++kc) {
          short8 kf =
              *(const short8*)&Ks[(mt * 32 + l31) * 72 + kc * 16 + hl * 8];
          st = __builtin_amdgcn_mfma_f32_32x32x16_bf16(kf, qf[qs][kc], st, 0, 0, 0);
        }
#pragma unroll
        for (int g = 0; g < 4; ++g) {
          float v0 = st[4 * g + 0]; v0 = v0 > 0.f ? v0 : 0.f;
          float v1 = st[4 * g + 1]; v1 = v1 > 0.f ? v1 : 0.f;
          float v2 = st[4 * g + 2]; v2 = v2 > 0.f ? v2 : 0.f;
          float v3 = st[4 * g + 3]; v3 = v3 > 0.f ? v3 : 0.f;
          den[qs] += (v0 + v1) + (v2 + v3);
          pk[mt][g * 2 + 0] = pkbf(v0, v1);
          pk[mt][g * 2 + 1] = pkbf(v2, v3);
        }
      }
      // C-layout -> PV B-operand layout entirely in registers:
      // B-frag[kc] lane(l31,hl) needs kv = kc*16 + hl*8 + j at q=l31.
      // X=pk[mt][gb*2+p], Y=pk[mt][(gb+1)*2+p]; permlane32_swap gives
      // X'={X.lo,Y.lo} (j=2p,2p+1), Y'={X.hi,Y.hi} (j=2p+4,2p+5).
#pragma unroll
      for (int kc = 0; kc < 4; ++kc) {
        const int mt = kc >> 1, gb = (kc & 1) * 2;
        unsigned int a0 = pk[mt][gb * 2 + 0], b0 = pk[mt][gb * 2 + 2];
        unsigned int a1 = pk[mt][gb * 2 + 1], b1 = pk[mt][gb * 2 + 3];
        asm("v_permlane32_swap_b32 %0, %1" : "+v"(a0), "+v"(b0));
        asm("v_permlane32_swap_b32 %0, %1" : "+v"(a1), "+v"(b1));
        union { unsigned int u[4]; short8 s; } pf;
        pf.u[0] = a0; pf.u[1] = a1; pf.u[2] = b0; pf.u[3] = b1;
#pragma unroll
        for (int dt = 0; dt < 2; ++dt) {
          short8 vb =
              *(const short8*)&Vs[(dt * 32 + l31) * 72 + kc * 16 + hl * 8];
          octx[qs][dt] = __builtin_amdgcn_mfma_f32_32x32x16_bf16(
              vb, pf.s, octx[qs][dt], 0, 0, 0);
        }
      }
    }
  }

  // ---- normalize + store; lane l31 owns q, all in registers ----
#pragma unroll
  for (int qs = 0; qs < 2; ++qs) {
    float d = den[qs] + __shfl_xor(den[qs], 32);
    const float sc = 1.f / (d + 8e-6f);   // folded 1/sqrt(64) scaling
    const size_t qrow = (size_t)(tb * 1024 + qt * 256 + w * 64 + qs * 32 + l31);
#pragma unroll
    for (int dt = 0; dt < 2; ++dt)
#pragma unroll
      for (int g = 0; g < 4; ++g) {
        const float v0 = octx[qs][dt][4 * g + 0] * sc;
        const float v1 = octx[qs][dt][4 * g + 1] * sc;
        const float v2 = octx[qs][dt][4 * g + 2] * sc;
        const float v3 = octx[qs][dt][4 * g + 3] * sc;
        uint2 u;
        u.x = pkbf(v0, v1);
        u.y = pkbf(v2, v3);
        *(uint2*)&ctx[qrow * 768 + h * 64 + dt * 32 + g * 8 + hl * 4] = u;
      }
  }
}

// ---------------------------------------------------------------------------
extern "C" void kernel_launch(void* const* d_in, const int* in_sizes, int n_in,
                              void* d_out, int out_size, void* d_ws, size_t ws_size,
                              hipStream_t stream) {
  const float* x  = (const float*)d_in[0];
  const float* Wq = (const float*)d_in[1];
  const float* bq = (const float*)d_in[2];
  const float* Wk = (const float*)d_in[3];
  const float* bk = (const float*)d_in[4];
  const float* Wv = (const float*)d_in[5];
  const float* bv = (const float*)d_in[6];
  const float* Wo = (const float*)d_in[7];
  const float* bo = (const float*)d_in[8];
  float* out = (float*)d_out;

  char* ws = (char*)d_ws;
  // workspace layout (bytes); CTX aliases XBF (XBF dead after QKV GEMM)
  unsigned short* XBF  = (unsigned short*)(ws);                  // 25165824 B
  unsigned short* CTX  = (unsigned short*)(ws);                  // alias
  unsigned short* WQKV = (unsigned short*)(ws + 25165824);       //  3538944 B
  unsigned short* WOb  = (unsigned short*)(ws + 28704768);       //  1179648 B
  unsigned short* QKV  = (unsigned short*)(ws + 29884416);       // 75497472 B
  unsigned short* VT   = (unsigned short*)(ws + 105381888);      // 25165824 B
  // total: 130547712 B

  cast_all<<<14592, 256, 0, stream>>>(x, Wq, Wk, Wv, Wo, XBF, WQKV, WOb);

  gemm_bt<true><<<dim3(18, 128), 256, 0, stream>>>(XBF, WQKV, QKV, nullptr, VT,
                                                   bq, bk, bv, 2304);
  attn32<<<dim3(192, 4), 256, 0, stream>>>(QKV, VT, CTX);
  gemm_bt<false><<<dim3(6, 128), 256, 0, stream>>>(CTX, WOb, nullptr, out,
                                                   nullptr, bo, bo, bo, 768);
}

// Round 5
// 316.374 us; speedup vs baseline: 1.0864x; 1.0864x over previous
//
#include <hip/hip_runtime.h>
#include <hip/hip_bf16.h>
#include <cstdint>

// ---------------------------------------------------------------------------
// TempoSpikeSelfAttention on MI355X (gfx950), bf16-MFMA pipeline.  v6
//   dims: T=4 B=4 N=1024 D=768 H=12 Dh=64 -> M = T*B*N = 16384 rows
// v6 changes (vs v5, 343.7 us measured):
//   * gemm_bt: double-buffered LDS prefetch (T3 "minimum 2-phase"):
//     stage tile kt+1 into buf^1 BEFORE computing tile kt; ONE barrier/iter.
//     v5 staged tile kt then immediately drained vmcnt(0) at the barrier ->
//     full load latency exposed every iteration (MfmaUtil 18.9%).
//   * gemm_bt: bijective XCD swizzle (nwg%8==0) so the 18 column-blocks
//     sharing an A-tile land on ONE XCD's L2 (FETCH was 135 MB vs ~29 ideal).
// Pipeline:
//   1. cast_all: x, Wq|Wk|Wv (concat), Wo -> bf16 (one dispatch)
//   2. QKV GEMM: QKV[16384, 2304] bf16, bias fused; V column-blocks written
//      TRANSPOSED straight to Vt[(tb*12+h)*64+d][n]
//   3. attn32 v4: grid (192 heads, 4 qt); S^T = K Q^T (mfma 32x32x16);
//      P C-layout -> B-layout in regs via v_permlane32_swap_b32;
//      octx += V^T P; L1-normalize in regs.
//   4. O GEMM: out = CTX @ Wo^T + bo -> fp32 d_out
// ---------------------------------------------------------------------------

typedef __attribute__((ext_vector_type(8))) short short8;     // 8 bf16 = 4 VGPR
typedef __attribute__((ext_vector_type(4))) float float4v;    // 16x16 acc
typedef __attribute__((ext_vector_type(16))) float float16v;  // 32x32 acc

__device__ __forceinline__ unsigned short f2bf(float f) {
  unsigned int u = __float_as_uint(f);
  u = (u + 0x7fffu + ((u >> 16) & 1u)) >> 16;   // RNE
  return (unsigned short)u;
}

// pack two f32 -> two bf16 (round-half-away) in one v_perm_b32
__device__ __forceinline__ unsigned int pkbf(float a, float b) {
  unsigned int ua = __float_as_uint(a) + 0x8000u;
  unsigned int ub = __float_as_uint(b) + 0x8000u;
  return __builtin_amdgcn_perm(ub, ua, 0x07060302u);  // [bf(a) lo16 | bf(b) hi16]
}

// async global->LDS, 16B per lane; LDS dest = wave-uniform base + lane*16
__device__ __forceinline__ void gld_lds16(const void* g, void* lds) {
  __builtin_amdgcn_global_load_lds(
      (__attribute__((address_space(1))) void*)(uintptr_t)g,
      (__attribute__((address_space(3))) void*)(uint32_t)(uintptr_t)lds,
      16, 0, 0);
}

// ---------------------------------------------------------------------------
// One dispatch for all fp32->bf16 casts. Block-uniform routing:
//   blocks [0,12288)        : x   (3145728 float4)
//   blocks [12288,12288+576): Wq -> WQKV[0]
//   next 576                : Wk -> WQKV+589824
//   next 576                : Wv -> WQKV+1179648
//   next 576                : Wo -> WOb
__global__ __launch_bounds__(256) void cast_all(
    const float* __restrict__ x,  const float* __restrict__ Wq,
    const float* __restrict__ Wk, const float* __restrict__ Wv,
    const float* __restrict__ Wo, unsigned short* __restrict__ XBF,
    unsigned short* __restrict__ WQKV, unsigned short* __restrict__ WOb) {
  const int bid = blockIdx.x;
  const float* src;
  unsigned short* dst;
  int i;
  if (bid < 12288) {
    src = x; dst = XBF; i = bid * 256 + threadIdx.x;
  } else {
    const int wb = bid - 12288;          // 0..2303
    const int which = wb / 576;
    i = (wb % 576) * 256 + threadIdx.x;  // < 147456
    src = (which == 0) ? Wq : (which == 1) ? Wk : (which == 2) ? Wv : Wo;
    dst = (which == 0) ? WQKV
        : (which == 1) ? WQKV + 589824
        : (which == 2) ? WQKV + 1179648 : WOb;
  }
  float4 f = reinterpret_cast<const float4*>(src)[i];
  ushort4 o;
  o.x = f2bf(f.x); o.y = f2bf(f.y); o.z = f2bf(f.z); o.w = f2bf(f.w);
  reinterpret_cast<ushort4*>(dst)[i] = o;
}

// ---------------------------------------------------------------------------
// C[i,j] = sum_k A[i,k] * Bt[j,k] + bias[j].  K=768 fixed. 128x128 tile, BK=32.
// 4 waves in 2x2, each 64x64 (4x4 mfma 16x16x32 tiles).
// Double-buffered LDS: prefetch tile kt+1 (global_load_lds) issued before
// compute of tile kt; single __syncthreads per iteration drains it.
// OUT_BF16 path: column-blocks with sel==2 (V) are written TRANSPOSED to Vt.
template <bool OUT_BF16>
__global__ __launch_bounds__(256) void gemm_bt(
    const unsigned short* __restrict__ A,   // [M,768] bf16
    const unsigned short* __restrict__ Bt,  // [N,768] bf16
    unsigned short* __restrict__ Cb,        // bf16 out [M,N]
    float* __restrict__ Cf,                 // f32 out  [M,N]
    unsigned short* __restrict__ Vt,        // bf16 out [(tb*12+h)*64+d][1024]
    const float* __restrict__ b0, const float* __restrict__ b1,
    const float* __restrict__ b2, int N) {
  constexpr int K = 768;
  __shared__ unsigned short As[2][128 * 32];   // row stride 32 el (64 B)
  __shared__ unsigned short Bs[2][128 * 32];

  const int tid = threadIdx.x;
  const int lane = tid & 63;
  const int w = tid >> 6;
  const int wrow = w >> 1, wcol = w & 1;
  const int l15 = lane & 15, quad = lane >> 4;

  // Bijective XCD swizzle: HW linear id (x-fastest) -> logical id so that
  // 8*per consecutive logical blocks (sharing A-tiles) sit on one XCD.
  const int gx = gridDim.x;
  const int nwg = gx * gridDim.y;                   // 2304 or 768; % 8 == 0
  const int hw = blockIdx.y * gx + blockIdx.x;
  const int per = nwg >> 3;
  const int lg = (hw & 7) * per + (hw >> 3);
  const int bx = lg % gx, by = lg / gx;
  const int i0 = by * 128, j0 = bx * 128;

  const unsigned short* ga = A + (size_t)(i0 + 32 * w + (lane >> 2)) * K + (lane & 3) * 8;
  const unsigned short* gb = Bt + (size_t)(j0 + 32 * w + (lane >> 2)) * K + (lane & 3) * 8;

  float4v acc[4][4];
#pragma unroll
  for (int a = 0; a < 4; ++a)
#pragma unroll
    for (int b = 0; b < 4; ++b) acc[a][b] = float4v{0.f, 0.f, 0.f, 0.f};

  // prologue: stage tile 0 into buffer 0
  gld_lds16(ga, &As[0][(32 * w) * 32]);
  gld_lds16(ga + 16 * K, &As[0][(32 * w + 16) * 32]);
  gld_lds16(gb, &Bs[0][(32 * w) * 32]);
  gld_lds16(gb + 16 * K, &Bs[0][(32 * w + 16) * 32]);
  __syncthreads();   // drains vmcnt -> tile 0 resident

#pragma unroll 1
  for (int kt = 0; kt < K / 32; ++kt) {
    const int cur = kt & 1;
    if (kt < K / 32 - 1) {          // prefetch tile kt+1 into other buffer
      const unsigned short* pa = ga + (kt + 1) * 32;
      const unsigned short* pb = gb + (kt + 1) * 32;
      gld_lds16(pa, &As[cur ^ 1][(32 * w) * 32]);
      gld_lds16(pa + 16 * K, &As[cur ^ 1][(32 * w + 16) * 32]);
      gld_lds16(pb, &Bs[cur ^ 1][(32 * w) * 32]);
      gld_lds16(pb + 16 * K, &Bs[cur ^ 1][(32 * w + 16) * 32]);
    }

    short8 af[4], bfr[4];
#pragma unroll
    for (int a = 0; a < 4; ++a)
      af[a] = *(const short8*)&As[cur][(wrow * 64 + a * 16 + l15) * 32 + quad * 8];
#pragma unroll
    for (int b = 0; b < 4; ++b)
      bfr[b] = *(const short8*)&Bs[cur][(wcol * 64 + b * 16 + l15) * 32 + quad * 8];
#pragma unroll
    for (int a = 0; a < 4; ++a)
#pragma unroll
      for (int b = 0; b < 4; ++b)
        acc[a][b] = __builtin_amdgcn_mfma_f32_16x16x32_bf16(af[a], bfr[b], acc[a][b], 0, 0, 0);
    // single barrier: (a) all reads of buf[cur] done before it is re-staged
    // next iter; (b) implicit vmcnt(0) drain -> prefetched tile resident.
    __syncthreads();
  }

  const int sel = j0 / 768;
  const float* bp = (sel == 0) ? b0 : ((sel == 1) ? b1 : b2);
#pragma unroll
  for (int a = 0; a < 4; ++a) {
    const int row0 = i0 + wrow * 64 + a * 16 + quad * 4;
#pragma unroll
    for (int b = 0; b < 4; ++b) {
      const int col = j0 + wcol * 64 + b * 16 + l15;
      const float bias = bp[col - sel * 768];
      if (OUT_BF16 && sel == 2) {
        // V block -> transposed store into Vt.
        const int tb = row0 >> 10;
        const int n0 = row0 & 1023;            // multiple of 4 -> 8B aligned
        const int hd = col - 1536;             // h*64 + d
        const float v0 = acc[a][b][0] + bias;
        const float v1 = acc[a][b][1] + bias;
        const float v2 = acc[a][b][2] + bias;
        const float v3 = acc[a][b][3] + bias;
        uint2 u;
        u.x = (unsigned int)f2bf(v0) | ((unsigned int)f2bf(v1) << 16);
        u.y = (unsigned int)f2bf(v2) | ((unsigned int)f2bf(v3) << 16);
        *(uint2*)&Vt[((size_t)(tb * 768 + hd)) * 1024 + n0] = u;
      } else {
#pragma unroll
        for (int r = 0; r < 4; ++r) {
          const float v = acc[a][b][r] + bias;
          if (OUT_BF16)
            Cb[(size_t)(row0 + r) * N + col] = f2bf(v);
          else
            Cf[(size_t)(row0 + r) * N + col] = v;
        }
      }
    }
  }
}

// ---------------------------------------------------------------------------
// Attention v4. Grid (tbh=192, qt=4); 256 thr = 4 waves; wave = 64 q (2 x 32).
__global__ __launch_bounds__(256) void attn32(
    const unsigned short* __restrict__ qkv,  // [16384, 2304] bf16
    const unsigned short* __restrict__ vt,   // [(tbh)*64 + d][1024] bf16
    unsigned short* __restrict__ ctx) {      // [16384, 768] bf16
  __shared__ unsigned short Ks[64 * 72];     // [kv_local][d], padded
  __shared__ unsigned short Vs[64 * 72];     // [d][kv_local], padded

  const int tbh = blockIdx.x;                // same-head blocks: ids 192 apart
  const int qt = blockIdx.y;                 // -> same XCD (192 % 8 == 0)
  const int tb = tbh / 12, h = tbh % 12;
  const int tid = threadIdx.x, lane = tid & 63, w = tid >> 6;
  const int l31 = lane & 31, hl = lane >> 5;

  // ---- Q fragments: one-time scattered global loads ----
  short8 qf[2][4];   // [qs][kc]: B-op: lane holds Q[q=.. +l31][kc*16+hl*8+j]
#pragma unroll
  for (int qs = 0; qs < 2; ++qs) {
    const unsigned short* qp =
        qkv + (size_t)(tb * 1024 + qt * 256 + w * 64 + qs * 32 + l31) * 2304 +
        h * 64 + hl * 8;
#pragma unroll
    for (int kc = 0; kc < 4; ++kc) qf[qs][kc] = *(const short8*)(qp + kc * 16);
  }

  // ---- staging: 256 thr cover 64 rows x 8 chunks of 16B, 2 rows/thread ----
  const int srow = tid >> 3;   // 0..31 (and +32)
  const int sblk = tid & 7;
  const unsigned short* kcol =
      qkv + (size_t)(tb * 1024) * 2304 + 768 + h * 64 + sblk * 8;
  const unsigned short* vcol = vt + ((size_t)tbh * 64 + srow) * 1024 + sblk * 8;
  uint4 kr0, kr1, vr0, vr1;
  auto loadKV = [&](int kv) {
    const unsigned short* kp = kcol + (size_t)(kv * 64 + srow) * 2304;
    kr0 = *(const uint4*)kp;
    kr1 = *(const uint4*)(kp + 32 * 2304);
    const unsigned short* vp = vcol + kv * 64;
    vr0 = *(const uint4*)vp;
    vr1 = *(const uint4*)(vp + 32 * 1024);
  };

  float16v octx[2][2];   // [qs][dt]; C: row=d_local, col=q=l31
#pragma unroll
  for (int qs = 0; qs < 2; ++qs)
#pragma unroll
    for (int dt = 0; dt < 2; ++dt)
#pragma unroll
      for (int i = 0; i < 16; ++i) octx[qs][dt][i] = 0.f;
  float den[2] = {0.f, 0.f};

  loadKV(0);

#pragma unroll 1
  for (int kv = 0; kv < 16; ++kv) {
    __syncthreads();   // #1: all reads of tile kv-1 done; drains loads of kv
    *(uint4*)&Ks[srow * 72 + sblk * 8] = kr0;
    *(uint4*)&Ks[(srow + 32) * 72 + sblk * 8] = kr1;
    *(uint4*)&Vs[srow * 72 + sblk * 8] = vr0;
    *(uint4*)&Vs[(srow + 32) * 72 + sblk * 8] = vr1;
    __syncthreads();   // #2: writes visible (vmcnt trivially 0 here)
    if (kv < 15) loadKV(kv + 1);   // in flight across compute below

#pragma unroll
    for (int qs = 0; qs < 2; ++qs) {
      // S^T = K.Q^T, then relu+den+pack (C: col=q=l31, row=kv=4hl+(r)+8g+32mt)
      unsigned int pk[2][8];   // [mt][g*2+p]
#pragma unroll
      for (int mt = 0; mt < 2; ++mt) {
        float16v st;
#pragma unroll
        for (int i = 0; i < 16; ++i) st[i] = 0.f;
#pragma unroll
        for (int kc = 0; kc < 4; ++kc) {
          short8 kf =
              *(const short8*)&Ks[(mt * 32 + l31) * 72 + kc * 16 + hl * 8];
          st = __builtin_amdgcn_mfma_f32_32x32x16_bf16(kf, qf[qs][kc], st, 0, 0, 0);
        }
#pragma unroll
        for (int g = 0; g < 4; ++g) {
          float v0 = st[4 * g + 0]; v0 = v0 > 0.f ? v0 : 0.f;
          float v1 = st[4 * g + 1]; v1 = v1 > 0.f ? v1 : 0.f;
          float v2 = st[4 * g + 2]; v2 = v2 > 0.f ? v2 : 0.f;
          float v3 = st[4 * g + 3]; v3 = v3 > 0.f ? v3 : 0.f;
          den[qs] += (v0 + v1) + (v2 + v3);
          pk[mt][g * 2 + 0] = pkbf(v0, v1);
          pk[mt][g * 2 + 1] = pkbf(v2, v3);
        }
      }
      // C-layout -> PV B-operand layout entirely in registers.
#pragma unroll
      for (int kc = 0; kc < 4; ++kc) {
        const int mt = kc >> 1, gb = (kc & 1) * 2;
        unsigned int a0 = pk[mt][gb * 2 + 0], b0 = pk[mt][gb * 2 + 2];
        unsigned int a1 = pk[mt][gb * 2 + 1], b1 = pk[mt][gb * 2 + 3];
        asm("v_permlane32_swap_b32 %0, %1" : "+v"(a0), "+v"(b0));
        asm("v_permlane32_swap_b32 %0, %1" : "+v"(a1), "+v"(b1));
        union { unsigned int u[4]; short8 s; } pf;
        pf.u[0] = a0; pf.u[1] = a1; pf.u[2] = b0; pf.u[3] = b1;
#pragma unroll
        for (int dt = 0; dt < 2; ++dt) {
          short8 vb =
              *(const short8*)&Vs[(dt * 32 + l31) * 72 + kc * 16 + hl * 8];
          octx[qs][dt] = __builtin_amdgcn_mfma_f32_32x32x16_bf16(
              vb, pf.s, octx[qs][dt], 0, 0, 0);
        }
      }
    }
  }

  // ---- normalize + store; lane l31 owns q, all in registers ----
#pragma unroll
  for (int qs = 0; qs < 2; ++qs) {
    float d = den[qs] + __shfl_xor(den[qs], 32);
    const float sc = 1.f / (d + 8e-6f);   // folded 1/sqrt(64) scaling
    const size_t qrow = (size_t)(tb * 1024 + qt * 256 + w * 64 + qs * 32 + l31);
#pragma unroll
    for (int dt = 0; dt < 2; ++dt)
#pragma unroll
      for (int g = 0; g < 4; ++g) {
        const float v0 = octx[qs][dt][4 * g + 0] * sc;
        const float v1 = octx[qs][dt][4 * g + 1] * sc;
        const float v2 = octx[qs][dt][4 * g + 2] * sc;
        const float v3 = octx[qs][dt][4 * g + 3] * sc;
        uint2 u;
        u.x = pkbf(v0, v1);
        u.y = pkbf(v2, v3);
        *(uint2*)&ctx[qrow * 768 + h * 64 + dt * 32 + g * 8 + hl * 4] = u;
      }
  }
}

// ---------------------------------------------------------------------------
extern "C" void kernel_launch(void* const* d_in, const int* in_sizes, int n_in,
                              void* d_out, int out_size, void* d_ws, size_t ws_size,
                              hipStream_t stream) {
  const float* x  = (const float*)d_in[0];
  const float* Wq = (const float*)d_in[1];
  const float* bq = (const float*)d_in[2];
  const float* Wk = (const float*)d_in[3];
  const float* bk = (const float*)d_in[4];
  const float* Wv = (const float*)d_in[5];
  const float* bv = (const float*)d_in[6];
  const float* Wo = (const float*)d_in[7];
  const float* bo = (const float*)d_in[8];
  float* out = (float*)d_out;

  char* ws = (char*)d_ws;
  // workspace layout (bytes); CTX aliases XBF (XBF dead after QKV GEMM)
  unsigned short* XBF  = (unsigned short*)(ws);                  // 25165824 B
  unsigned short* CTX  = (unsigned short*)(ws);                  // alias
  unsigned short* WQKV = (unsigned short*)(ws + 25165824);       //  3538944 B
  unsigned short* WOb  = (unsigned short*)(ws + 28704768);       //  1179648 B
  unsigned short* QKV  = (unsigned short*)(ws + 29884416);       // 75497472 B
  unsigned short* VT   = (unsigned short*)(ws + 105381888);      // 25165824 B
  // total: 130547712 B

  cast_all<<<14592, 256, 0, stream>>>(x, Wq, Wk, Wv, Wo, XBF, WQKV, WOb);

  gemm_bt<true><<<dim3(18, 128), 256, 0, stream>>>(XBF, WQKV, QKV, nullptr, VT,
                                                   bq, bk, bv, 2304);
  attn32<<<dim3(192, 4), 256, 0, stream>>>(QKV, VT, CTX);
  gemm_bt<false><<<dim3(6, 128), 256, 0, stream>>>(CTX, WOb, nullptr, out,
                                                   nullptr, bo, bo, bo, 768);
}

// Round 7
// 313.520 us; speedup vs baseline: 1.0963x; 1.0091x over previous
//
#include <hip/hip_runtime.h>
#include <hip/hip_bf16.h>
#include <cstdint>

// ---------------------------------------------------------------------------
// TempoSpikeSelfAttention on MI355X (gfx950), bf16-MFMA pipeline.  v7
//   dims: T=4 B=4 N=1024 D=768 H=12 Dh=64 -> M = T*B*N = 16384 rows
// v7 changes (vs v6, 316.4 us measured; QKV GEMM 113 us, MfmaUtil 21%):
//   * gemm_bt: 3-buffer 2-deep pipeline with COUNTED vmcnt (T4):
//     iter kt issues loads for kt+2, computes kt, then waits vmcnt(4)
//     (= only tile kt+1's loads; kt+2's stay in flight) + raw s_barrier.
//     v6's __syncthreads drained vmcnt(0) every iter -> ~900cy exposed
//     latency per 24 iters (model: 1250 cyc/iter measured vs ~180 compute).
// Pipeline:
//   1. cast_all: x, Wq|Wk|Wv (concat), Wo -> bf16 (one dispatch)
//   2. QKV GEMM: QKV[16384, 2304] bf16, bias fused; V column-blocks written
//      TRANSPOSED straight to Vt[(tb*12+h)*64+d][n]
//   3. attn32 v4: grid (192 heads, 4 qt); S^T = K Q^T (mfma 32x32x16);
//      P C-layout -> B-layout in regs via v_permlane32_swap_b32;
//      octx += V^T P; L1-normalize in regs.
//   4. O GEMM: out = CTX @ Wo^T + bo -> fp32 d_out
// ---------------------------------------------------------------------------

typedef __attribute__((ext_vector_type(8))) short short8;     // 8 bf16 = 4 VGPR
typedef __attribute__((ext_vector_type(4))) float float4v;    // 16x16 acc
typedef __attribute__((ext_vector_type(16))) float float16v;  // 32x32 acc

__device__ __forceinline__ unsigned short f2bf(float f) {
  unsigned int u = __float_as_uint(f);
  u = (u + 0x7fffu + ((u >> 16) & 1u)) >> 16;   // RNE
  return (unsigned short)u;
}

// pack two f32 -> two bf16 (round-half-away) in one v_perm_b32
__device__ __forceinline__ unsigned int pkbf(float a, float b) {
  unsigned int ua = __float_as_uint(a) + 0x8000u;
  unsigned int ub = __float_as_uint(b) + 0x8000u;
  return __builtin_amdgcn_perm(ub, ua, 0x07060302u);  // [bf(a) lo16 | bf(b) hi16]
}

// async global->LDS, 16B per lane; LDS dest = wave-uniform base + lane*16
__device__ __forceinline__ void gld_lds16(const void* g, void* lds) {
  __builtin_amdgcn_global_load_lds(
      (__attribute__((address_space(1))) void*)(uintptr_t)g,
      (__attribute__((address_space(3))) void*)(uint32_t)(uintptr_t)lds,
      16, 0, 0);
}

// ---------------------------------------------------------------------------
// One dispatch for all fp32->bf16 casts. Block-uniform routing:
//   blocks [0,12288)        : x   (3145728 float4)
//   blocks [12288,12288+576): Wq -> WQKV[0]
//   next 576                : Wk -> WQKV+589824
//   next 576                : Wv -> WQKV+1179648
//   next 576                : Wo -> WOb
__global__ __launch_bounds__(256) void cast_all(
    const float* __restrict__ x,  const float* __restrict__ Wq,
    const float* __restrict__ Wk, const float* __restrict__ Wv,
    const float* __restrict__ Wo, unsigned short* __restrict__ XBF,
    unsigned short* __restrict__ WQKV, unsigned short* __restrict__ WOb) {
  const int bid = blockIdx.x;
  const float* src;
  unsigned short* dst;
  int i;
  if (bid < 12288) {
    src = x; dst = XBF; i = bid * 256 + threadIdx.x;
  } else {
    const int wb = bid - 12288;          // 0..2303
    const int which = wb / 576;
    i = (wb % 576) * 256 + threadIdx.x;  // < 147456
    src = (which == 0) ? Wq : (which == 1) ? Wk : (which == 2) ? Wv : Wo;
    dst = (which == 0) ? WQKV
        : (which == 1) ? WQKV + 589824
        : (which == 2) ? WQKV + 1179648 : WOb;
  }
  float4 f = reinterpret_cast<const float4*>(src)[i];
  ushort4 o;
  o.x = f2bf(f.x); o.y = f2bf(f.y); o.z = f2bf(f.z); o.w = f2bf(f.w);
  reinterpret_cast<ushort4*>(dst)[i] = o;
}

// ---------------------------------------------------------------------------
// C[i,j] = sum_k A[i,k] * Bt[j,k] + bias[j].  K=768 fixed. 128x128 tile, BK=32.
// 4 waves in 2x2, each 64x64 (4x4 mfma 16x16x32 tiles).
// 3-buffer 2-deep pipeline, counted vmcnt (never 0 in steady state):
//   iter kt: stage tile kt+2 -> buf[(kt+2)%3]; ds_read+MFMA buf[kt%3];
//            s_waitcnt vmcnt(4) (tile kt+1 resident, kt+2 in flight);
//            raw s_barrier.
// Hazards: WAR on buf[(kt+2)%3] safe (last read iter kt-1; all waves' reads
// complete before end-of-(kt-1) barrier; overwrite issued after it).
// OUT_BF16 path: column-blocks with sel==2 (V) are written TRANSPOSED to Vt.
template <bool OUT_BF16>
__global__ __launch_bounds__(256) void gemm_bt(
    const unsigned short* __restrict__ A,   // [M,768] bf16
    const unsigned short* __restrict__ Bt,  // [N,768] bf16
    unsigned short* __restrict__ Cb,        // bf16 out [M,N]
    float* __restrict__ Cf,                 // f32 out  [M,N]
    unsigned short* __restrict__ Vt,        // bf16 out [(tb*12+h)*64+d][1024]
    const float* __restrict__ b0, const float* __restrict__ b1,
    const float* __restrict__ b2, int N) {
  constexpr int K = 768;
  constexpr int KT = K / 32;                   // 24 K-tiles
  __shared__ unsigned short As[3][128 * 32];   // row stride 32 el (64 B)
  __shared__ unsigned short Bs[3][128 * 32];

  const int tid = threadIdx.x;
  const int lane = tid & 63;
  const int w = tid >> 6;
  const int wrow = w >> 1, wcol = w & 1;
  const int l15 = lane & 15, quad = lane >> 4;

  // Bijective XCD swizzle: HW linear id (x-fastest) -> logical id so that
  // 8*per consecutive logical blocks (sharing A-tiles) sit on one XCD.
  const int gx = gridDim.x;
  const int nwg = gx * gridDim.y;                   // 2304 or 768; % 8 == 0
  const int hw = blockIdx.y * gx + blockIdx.x;
  const int per = nwg >> 3;
  const int lg = (hw & 7) * per + (hw >> 3);
  const int bx = lg % gx, by = lg / gx;
  const int i0 = by * 128, j0 = bx * 128;

  const unsigned short* ga = A + (size_t)(i0 + 32 * w + (lane >> 2)) * K + (lane & 3) * 8;
  const unsigned short* gb = Bt + (size_t)(j0 + 32 * w + (lane >> 2)) * K + (lane & 3) * 8;

  // stage K-tile kt2 into LDS buffer bufi (4 gld_lds per wave)
  auto stage = [&](int kt2, int bufi) {
    const unsigned short* pa = ga + kt2 * 32;
    const unsigned short* pb = gb + kt2 * 32;
    gld_lds16(pa, &As[bufi][(32 * w) * 32]);
    gld_lds16(pa + 16 * K, &As[bufi][(32 * w + 16) * 32]);
    gld_lds16(pb, &Bs[bufi][(32 * w) * 32]);
    gld_lds16(pb + 16 * K, &Bs[bufi][(32 * w + 16) * 32]);
  };

  float4v acc[4][4];
#pragma unroll
  for (int a = 0; a < 4; ++a)
#pragma unroll
    for (int b = 0; b < 4; ++b) acc[a][b] = float4v{0.f, 0.f, 0.f, 0.f};

  // prologue: 2 tiles in flight; wait for tile 0 only (vmcnt(4))
  stage(0, 0);
  stage(1, 1);
  asm volatile("s_waitcnt vmcnt(4)" ::: "memory");
  __builtin_amdgcn_s_barrier();
  __builtin_amdgcn_sched_barrier(0);

#pragma unroll 1
  for (int kt = 0; kt < KT; ++kt) {
    const int cur = kt % 3;
    if (kt + 2 < KT) stage(kt + 2, (kt + 2) % 3);  // 2-deep prefetch

    short8 af[4], bfr[4];
#pragma unroll
    for (int a = 0; a < 4; ++a)
      af[a] = *(const short8*)&As[cur][(wrow * 64 + a * 16 + l15) * 32 + quad * 8];
#pragma unroll
    for (int b = 0; b < 4; ++b)
      bfr[b] = *(const short8*)&Bs[cur][(wcol * 64 + b * 16 + l15) * 32 + quad * 8];
#pragma unroll
    for (int a = 0; a < 4; ++a)
#pragma unroll
      for (int b = 0; b < 4; ++b)
        acc[a][b] = __builtin_amdgcn_mfma_f32_16x16x32_bf16(af[a], bfr[b], acc[a][b], 0, 0, 0);

    // gate tile kt+1 residency; keep tile kt+2's 4 loads in flight
    if (kt + 2 < KT) {
      asm volatile("s_waitcnt vmcnt(4)" ::: "memory");
      __builtin_amdgcn_s_barrier();
      __builtin_amdgcn_sched_barrier(0);
    } else if (kt + 1 < KT) {
      asm volatile("s_waitcnt vmcnt(0)" ::: "memory");
      __builtin_amdgcn_s_barrier();
      __builtin_amdgcn_sched_barrier(0);
    }
    // last iter: no barrier; epilogue touches no LDS
  }

  const int sel = j0 / 768;
  const float* bp = (sel == 0) ? b0 : ((sel == 1) ? b1 : b2);
#pragma unroll
  for (int a = 0; a < 4; ++a) {
    const int row0 = i0 + wrow * 64 + a * 16 + quad * 4;
#pragma unroll
    for (int b = 0; b < 4; ++b) {
      const int col = j0 + wcol * 64 + b * 16 + l15;
      const float bias = bp[col - sel * 768];
      if (OUT_BF16 && sel == 2) {
        // V block -> transposed store into Vt.
        const int tb = row0 >> 10;
        const int n0 = row0 & 1023;            // multiple of 4 -> 8B aligned
        const int hd = col - 1536;             // h*64 + d
        const float v0 = acc[a][b][0] + bias;
        const float v1 = acc[a][b][1] + bias;
        const float v2 = acc[a][b][2] + bias;
        const float v3 = acc[a][b][3] + bias;
        uint2 u;
        u.x = (unsigned int)f2bf(v0) | ((unsigned int)f2bf(v1) << 16);
        u.y = (unsigned int)f2bf(v2) | ((unsigned int)f2bf(v3) << 16);
        *(uint2*)&Vt[((size_t)(tb * 768 + hd)) * 1024 + n0] = u;
      } else {
#pragma unroll
        for (int r = 0; r < 4; ++r) {
          const float v = acc[a][b][r] + bias;
          if (OUT_BF16)
            Cb[(size_t)(row0 + r) * N + col] = f2bf(v);
          else
            Cf[(size_t)(row0 + r) * N + col] = v;
        }
      }
    }
  }
}

// ---------------------------------------------------------------------------
// Attention v4. Grid (tbh=192, qt=4); 256 thr = 4 waves; wave = 64 q (2 x 32).
__global__ __launch_bounds__(256) void attn32(
    const unsigned short* __restrict__ qkv,  // [16384, 2304] bf16
    const unsigned short* __restrict__ vt,   // [(tbh)*64 + d][1024] bf16
    unsigned short* __restrict__ ctx) {      // [16384, 768] bf16
  __shared__ unsigned short Ks[64 * 72];     // [kv_local][d], padded
  __shared__ unsigned short Vs[64 * 72];     // [d][kv_local], padded

  const int tbh = blockIdx.x;                // same-head blocks: ids 192 apart
  const int qt = blockIdx.y;                 // -> same XCD (192 % 8 == 0)
  const int tb = tbh / 12, h = tbh % 12;
  const int tid = threadIdx.x, lane = tid & 63, w = tid >> 6;
  const int l31 = lane & 31, hl = lane >> 5;

  // ---- Q fragments: one-time scattered global loads ----
  short8 qf[2][4];   // [qs][kc]: B-op: lane holds Q[q=.. +l31][kc*16+hl*8+j]
#pragma unroll
  for (int qs = 0; qs < 2; ++qs) {
    const unsigned short* qp =
        qkv + (size_t)(tb * 1024 + qt * 256 + w * 64 + qs * 32 + l31) * 2304 +
        h * 64 + hl * 8;
#pragma unroll
    for (int kc = 0; kc < 4; ++kc) qf[qs][kc] = *(const short8*)(qp + kc * 16);
  }

  // ---- staging: 256 thr cover 64 rows x 8 chunks of 16B, 2 rows/thread ----
  const int srow = tid >> 3;   // 0..31 (and +32)
  const int sblk = tid & 7;
  const unsigned short* kcol =
      qkv + (size_t)(tb * 1024) * 2304 + 768 + h * 64 + sblk * 8;
  const unsigned short* vcol = vt + ((size_t)tbh * 64 + srow) * 1024 + sblk * 8;
  uint4 kr0, kr1, vr0, vr1;
  auto loadKV = [&](int kv) {
    const unsigned short* kp = kcol + (size_t)(kv * 64 + srow) * 2304;
    kr0 = *(const uint4*)kp;
    kr1 = *(const uint4*)(kp + 32 * 2304);
    const unsigned short* vp = vcol + kv * 64;
    vr0 = *(const uint4*)vp;
    vr1 = *(const uint4*)(vp + 32 * 1024);
  };

  float16v octx[2][2];   // [qs][dt]; C: row=d_local, col=q=l31
#pragma unroll
  for (int qs = 0; qs < 2; ++qs)
#pragma unroll
    for (int dt = 0; dt < 2; ++dt)
#pragma unroll
      for (int i = 0; i < 16; ++i) octx[qs][dt][i] = 0.f;
  float den[2] = {0.f, 0.f};

  loadKV(0);

#pragma unroll 1
  for (int kv = 0; kv < 16; ++kv) {
    __syncthreads();   // #1: all reads of tile kv-1 done; drains loads of kv
    *(uint4*)&Ks[srow * 72 + sblk * 8] = kr0;
    *(uint4*)&Ks[(srow + 32) * 72 + sblk * 8] = kr1;
    *(uint4*)&Vs[srow * 72 + sblk * 8] = vr0;
    *(uint4*)&Vs[(srow + 32) * 72 + sblk * 8] = vr1;
    __syncthreads();   // #2: writes visible (vmcnt trivially 0 here)
    if (kv < 15) loadKV(kv + 1);   // in flight across compute below

#pragma unroll
    for (int qs = 0; qs < 2; ++qs) {
      // S^T = K.Q^T, then relu+den+pack (C: col=q=l31, row=kv=4hl+(r)+8g+32mt)
      unsigned int pk[2][8];   // [mt][g*2+p]
#pragma unroll
      for (int mt = 0; mt < 2; ++mt) {
        float16v st;
#pragma unroll
        for (int i = 0; i < 16; ++i) st[i] = 0.f;
#pragma unroll
        for (int kc = 0; kc < 4; ++kc) {
          short8 kf =
              *(const short8*)&Ks[(mt * 32 + l31) * 72 + kc * 16 + hl * 8];
          st = __builtin_amdgcn_mfma_f32_32x32x16_bf16(kf, qf[qs][kc], st, 0, 0, 0);
        }
#pragma unroll
        for (int g = 0; g < 4; ++g) {
          float v0 = st[4 * g + 0]; v0 = v0 > 0.f ? v0 : 0.f;
          float v1 = st[4 * g + 1]; v1 = v1 > 0.f ? v1 : 0.f;
          float v2 = st[4 * g + 2]; v2 = v2 > 0.f ? v2 : 0.f;
          float v3 = st[4 * g + 3]; v3 = v3 > 0.f ? v3 : 0.f;
          den[qs] += (v0 + v1) + (v2 + v3);
          pk[mt][g * 2 + 0] = pkbf(v0, v1);
          pk[mt][g * 2 + 1] = pkbf(v2, v3);
        }
      }
      // C-layout -> PV B-operand layout entirely in registers.
#pragma unroll
      for (int kc = 0; kc < 4; ++kc) {
        const int mt = kc >> 1, gb = (kc & 1) * 2;
        unsigned int a0 = pk[mt][gb * 2 + 0], b0 = pk[mt][gb * 2 + 2];
        unsigned int a1 = pk[mt][gb * 2 + 1], b1 = pk[mt][gb * 2 + 3];
        asm("v_permlane32_swap_b32 %0, %1" : "+v"(a0), "+v"(b0));
        asm("v_permlane32_swap_b32 %0, %1" : "+v"(a1), "+v"(b1));
        union { unsigned int u[4]; short8 s; } pf;
        pf.u[0] = a0; pf.u[1] = a1; pf.u[2] = b0; pf.u[3] = b1;
#pragma unroll
        for (int dt = 0; dt < 2; ++dt) {
          short8 vb =
              *(const short8*)&Vs[(dt * 32 + l31) * 72 + kc * 16 + hl * 8];
          octx[qs][dt] = __builtin_amdgcn_mfma_f32_32x32x16_bf16(
              vb, pf.s, octx[qs][dt], 0, 0, 0);
        }
      }
    }
  }

  // ---- normalize + store; lane l31 owns q, all in registers ----
#pragma unroll
  for (int qs = 0; qs < 2; ++qs) {
    float d = den[qs] + __shfl_xor(den[qs], 32);
    const float sc = 1.f / (d + 8e-6f);   // folded 1/sqrt(64) scaling
    const size_t qrow = (size_t)(tb * 1024 + qt * 256 + w * 64 + qs * 32 + l31);
#pragma unroll
    for (int dt = 0; dt < 2; ++dt)
#pragma unroll
      for (int g = 0; g < 4; ++g) {
        const float v0 = octx[qs][dt][4 * g + 0] * sc;
        const float v1 = octx[qs][dt][4 * g + 1] * sc;
        const float v2 = octx[qs][dt][4 * g + 2] * sc;
        const float v3 = octx[qs][dt][4 * g + 3] * sc;
        uint2 u;
        u.x = pkbf(v0, v1);
        u.y = pkbf(v2, v3);
        *(uint2*)&ctx[qrow * 768 + h * 64 + dt * 32 + g * 8 + hl * 4] = u;
      }
  }
}

// ---------------------------------------------------------------------------
extern "C" void kernel_launch(void* const* d_in, const int* in_sizes, int n_in,
                              void* d_out, int out_size, void* d_ws, size_t ws_size,
                              hipStream_t stream) {
  const float* x  = (const float*)d_in[0];
  const float* Wq = (const float*)d_in[1];
  const float* bq = (const float*)d_in[2];
  const float* Wk = (const float*)d_in[3];
  const float* bk = (const float*)d_in[4];
  const float* Wv = (const float*)d_in[5];
  const float* bv = (const float*)d_in[6];
  const float* Wo = (const float*)d_in[7];
  const float* bo = (const float*)d_in[8];
  float* out = (float*)d_out;

  char* ws = (char*)d_ws;
  // workspace layout (bytes); CTX aliases XBF (XBF dead after QKV GEMM)
  unsigned short* XBF  = (unsigned short*)(ws);                  // 25165824 B
  unsigned short* CTX  = (unsigned short*)(ws);                  // alias
  unsigned short* WQKV = (unsigned short*)(ws + 25165824);       //  3538944 B
  unsigned short* WOb  = (unsigned short*)(ws + 28704768);       //  1179648 B
  unsigned short* QKV  = (unsigned short*)(ws + 29884416);       // 75497472 B
  unsigned short* VT   = (unsigned short*)(ws + 105381888);      // 25165824 B
  // total: 130547712 B

  cast_all<<<14592, 256, 0, stream>>>(x, Wq, Wk, Wv, Wo, XBF, WQKV, WOb);

  gemm_bt<true><<<dim3(18, 128), 256, 0, stream>>>(XBF, WQKV, QKV, nullptr, VT,
                                                   bq, bk, bv, 2304);
  attn32<<<dim3(192, 4), 256, 0, stream>>>(QKV, VT, CTX);
  gemm_bt<false><<<dim3(6, 128), 256, 0, stream>>>(CTX, WOb, nullptr, out,
                                                   nullptr, bo, bo, bo, 768);
}